// Round 6
// baseline (571.980 us; speedup 1.0000x reference)
//
#include <hip/hip_runtime.h>

// CTRNN: T=512, B=256, I=64, H=256.
//   pre = x_t @ W_in^T + b_in + h @ W_hh^T + b_hh + noise_t
//   h   = max(0.8*h + 0.2*pre, 0)
//
// R5 results: prex3 183us + rec(R0) 374us = 557us. Allocator datum: 512-thr
// launch_bounds(512,2) gets 128-VGPR budget (no spill at ~90 live); 256/1024
// -thr shapes got 64 and spilled. rec reproduced R0 exactly (VGPR=48,
// VALUBusy 80%, 0 conflicts).
//
// R6 theory: rec's 1752 cyc/step vs 512-cyc FMA floor is the 2x
// __syncthreads-per-step vmcnt(0) drain (m97 barrier-drain): barrier 1
// drains the t+2 prex prefetch (L3 ~400-600cy vs ~260cy of cover), barrier
// 2 drains the out-store ack. Hazard audit: both barriers only order LDS
// (pbuf no WAR: next write is after barrier 2; hbuf double-buffered; out
// write-only; prex read-only) -> lgkm-only asm barriers (pattern verified
// correct in R1/R3 runs). Single-variable A/B vs R0-rec.
// prex3b: batch 4 pairs per burst (32 indep broadcast b128 + 128 FMA before
// the shfl/store group) to cover LDS latency; chunk barriers lgkm-only too.

#define T_STEPS 512
#define BATCH   256
#define INSZ    64
#define HID     256
#define ALPHA_F 0.2f
#define OMA_F   0.8f

// LDS-only barrier: drains this wave's LDS ops, then s_barrier. Outstanding
// GLOBAL loads/stores stay in flight across it (no vmcnt drain).
#define LGKM_BARRIER() asm volatile("s_waitcnt lgkmcnt(0)\n\ts_barrier" ::: "memory")

// ---------------------------------------------------------------------------
// Kernel 1: prex = x @ W_in^T + b_in + b_hh + noise(t)   [biases folded]
// 512 blocks x 512 threads. Block bb owns pairs [256*bb, 256*bb+256) == all
// of batch for t = bb. Wave wv covers cols [32*wv,32*wv+32); lane&31 = col,
// lane>>5 = k-half. Each thread: w[32] (k-half of its col) -> ~60 live
// floats, no spill at the proven (512,2) shape.
// ---------------------------------------------------------------------------
__global__ __launch_bounds__(512, 2)
void ctrnn_prex3(const float* __restrict__ x,      // [T, B, I]
                 const float* __restrict__ noise,  // [T, H]
                 const float* __restrict__ W_in,   // [H, I]
                 const float* __restrict__ b_in,   // [H]
                 const float* __restrict__ b_hh,   // [H]
                 float* __restrict__ prex)         // [T, B, H] (ws)
{
    const int tid  = threadIdx.x;
    const int lane = tid & 63;
    const int wv   = tid >> 6;          // 0..7 -> column group
    const int cl   = lane & 31;         // col within group
    const int hf   = lane >> 5;         // k-half: 0 -> [0,32), 1 -> [32,64)
    const int col  = wv * 32 + cl;      // 0..255
    const int bb   = blockIdx.x;        // == t (256 pairs per block)
    const int p0   = bb * 256;

    __shared__ __align__(16) float xs[2][32][INSZ];   // 8 KB x 2, dbuf

    float w[32];
    {
        const float* wr = &W_in[col * INSZ + hf * 32];
#pragma unroll
        for (int k = 0; k < 32; k += 4) {
            float4 v = *reinterpret_cast<const float4*>(&wr[k]);
            w[k] = v.x; w[k+1] = v.y; w[k+2] = v.z; w[k+3] = v.w;
        }
    }
    const float bias = b_in[col] + b_hh[col] + noise[bb * HID + col];

    // stage chunk 0: 32 pairs x 64 floats = 512 float4, 1 per thread.
    {
        const float4* s4 = reinterpret_cast<const float4*>(&x[(size_t)p0 * INSZ]);
        reinterpret_cast<float4*>(&xs[0][0][0])[tid] = s4[tid];
    }
    __syncthreads();   // once; full drain harmless here

    const int khf = hf * 32;

    // one pair's k-half dot (8 broadcast b128 + 32 FMA), const-indexed
#define PX_DOT(PQ, SREG)                                                      \
    {                                                                         \
        float a0 = 0.f, a1 = 0.f, a2 = 0.f, a3 = 0.f;                         \
        _Pragma("unroll")                                                     \
        for (int k = 0; k < 32; k += 4) {                                     \
            float4 xv = *reinterpret_cast<const float4*>(                     \
                &xs[cur][pp + (PQ)][khf + k]);                                \
            a0 = fmaf(w[k],     xv.x, a0);                                    \
            a1 = fmaf(w[k + 1], xv.y, a1);                                    \
            a2 = fmaf(w[k + 2], xv.z, a2);                                    \
            a3 = fmaf(w[k + 3], xv.w, a3);                                    \
        }                                                                     \
        SREG = (a0 + a1) + (a2 + a3);                                         \
    }

#pragma unroll 1
    for (int c = 0; c < 8; ++c) {                 // 8 chunks x 32 pairs
        const int cur = c & 1;

        // issue next chunk's global load early; LDS-write after compute
        float4 st = make_float4(0.f, 0.f, 0.f, 0.f);
        if (c < 7) {
            st = reinterpret_cast<const float4*>(
                &x[(size_t)(p0 + (c + 1) * 32) * INSZ])[tid];
        }

        float* op = &prex[(size_t)(p0 + c * 32) * HID + col];
#pragma unroll 1
        for (int pp = 0; pp < 32; pp += 4) {
            // 4 independent chains: 32 b128 reads + 128 FMAs schedulable
            // before the shfl/store group (covers LDS latency).
            float s0, s1, s2, s3;
            PX_DOT(0, s0);
            PX_DOT(1, s1);
            PX_DOT(2, s2);
            PX_DOT(3, s3);
            s0 += __shfl_xor(s0, 32);             // combine k-halves in-wave
            s1 += __shfl_xor(s1, 32);
            s2 += __shfl_xor(s2, 32);
            s3 += __shfl_xor(s3, 32);
            if (hf == 0) {                        // 32 lanes x 4B, coalesced
                op[(size_t)(pp + 0) * HID] = s0 + bias;
                op[(size_t)(pp + 1) * HID] = s1 + bias;
                op[(size_t)(pp + 2) * HID] = s2 + bias;
                op[(size_t)(pp + 3) * HID] = s3 + bias;
            }
        }

        if (c < 7) {
            reinterpret_cast<float4*>(&xs[cur ^ 1][0][0])[tid] = st;
        }
        LGKM_BARRIER();   // publish xs writes; prex stores keep flying
    }
#undef PX_DOT
}

// ---------------------------------------------------------------------------
// Kernel 2: the recurrence. R0 structure (field-measured 376us, VGPR=48)
// with ONE change: both per-step __syncthreads -> lgkm-only barriers, so the
// t+2 prex prefetch and the out stores are never drained on the barrier.
// 256 blocks (1/batch) x 1024 threads (4 waves/SIMD).
// Thread (g=tid>>6, jj=tid&63): rows {jj+64m, m=0..3}, k in [16g,16g+16).
// ---------------------------------------------------------------------------
__global__ __launch_bounds__(1024, 4)
void ctrnn_rec(const float* __restrict__ hidden,  // [B, H]
               const float* __restrict__ prex,    // [T, B, H] (ws)
               const float* __restrict__ W_hh,    // [H, H]
               float* __restrict__ out)           // [T,B,H] ++ [B,H]
{
    const int tid = threadIdx.x;
    const int jj  = tid & 63;            // lane  -> row offset
    const int g   = tid >> 6;            // 0..15 -> k-chunk, wave-uniform
    const int b   = blockIdx.x;

    __shared__ __align__(16) float hbuf[2][HID];
    __shared__ __align__(16) float pbuf[16][HID];

    // Weights: 4 rows x 16 k = 64 floats, FULLY const-indexed -> arch VGPRs.
    float w[4][16];
#pragma unroll
    for (int m = 0; m < 4; ++m) {
        const float* wrow = &W_hh[(jj + 64 * m) * HID + 16 * g];
#pragma unroll
        for (int c = 0; c < 4; ++c) {
            float4 v = *reinterpret_cast<const float4*>(&wrow[4 * c]);
            w[m][4*c]   = v.x; w[m][4*c+1] = v.y;
            w[m][4*c+2] = v.z; w[m][4*c+3] = v.w;
        }
    }

    float hj = 0.f, pcur = 0.f, pn1 = 0.f;
    if (tid < HID) {                     // reduce/update threads: row r = tid
        hj = hidden[b * HID + tid];
        hbuf[0][tid] = hj;
        pcur = prex[(size_t)b * HID + tid];                       // t=0
        pn1  = prex[((size_t)1 * BATCH + b) * HID + tid];         // t=1
    }
    __syncthreads();                     // once, before the loop

    const int koff = 16 * g;
    int cur = 0;
#pragma unroll 1
    for (int t = 0; t < T_STEPS; ++t) {
        // 2-deep prefetch: issue load for t+2 at the top. With lgkm-only
        // barriers this load stays in flight across both barriers and has
        // ~2 full steps to complete before its value is consumed.
        float pn2 = 0.f;
        if (tid < HID && t + 2 < T_STEPS) {
            pn2 = prex[((size_t)(t + 2) * BATCH + b) * HID + tid];
        }

        // h-chunk read ONCE (4 broadcast b128), reused across 4 rows.
        float4 h0 = *reinterpret_cast<const float4*>(&hbuf[cur][koff]);
        float4 h1 = *reinterpret_cast<const float4*>(&hbuf[cur][koff + 4]);
        float4 h2 = *reinterpret_cast<const float4*>(&hbuf[cur][koff + 8]);
        float4 h3 = *reinterpret_cast<const float4*>(&hbuf[cur][koff + 12]);

        float acc[4];
#pragma unroll
        for (int m = 0; m < 4; ++m) {
            float a = 0.f, bq = 0.f;
            a  = fmaf(w[m][0],  h0.x, a);  bq = fmaf(w[m][1],  h0.y, bq);
            a  = fmaf(w[m][2],  h0.z, a);  bq = fmaf(w[m][3],  h0.w, bq);
            a  = fmaf(w[m][4],  h1.x, a);  bq = fmaf(w[m][5],  h1.y, bq);
            a  = fmaf(w[m][6],  h1.z, a);  bq = fmaf(w[m][7],  h1.w, bq);
            a  = fmaf(w[m][8],  h2.x, a);  bq = fmaf(w[m][9],  h2.y, bq);
            a  = fmaf(w[m][10], h2.z, a);  bq = fmaf(w[m][11], h2.w, bq);
            a  = fmaf(w[m][12], h3.x, a);  bq = fmaf(w[m][13], h3.y, bq);
            a  = fmaf(w[m][14], h3.z, a);  bq = fmaf(w[m][15], h3.w, bq);
            acc[m] = a + bq;
        }
        // Conflict-free partial writes (lanes -> consecutive rows).
        pbuf[g][jj]       = acc[0];
        pbuf[g][jj + 64]  = acc[1];
        pbuf[g][jj + 128] = acc[2];
        pbuf[g][jj + 192] = acc[3];
        LGKM_BARRIER();                  // partials visible; NO vmcnt drain

        const int nxt = cur ^ 1;
        if (tid < HID) {
            float s = pcur;
#pragma unroll
            for (int gg = 0; gg < 16; ++gg) s += pbuf[gg][tid];
            hj = fmaxf(fmaf(OMA_F, hj, ALPHA_F * s), 0.f);
            out[((size_t)t * BATCH + b) * HID + tid] = hj;   // fire-and-forget
            hbuf[nxt][tid] = hj;
            pcur = pn1; pn1 = pn2;
        }
        LGKM_BARRIER();                  // hbuf[nxt] published; stores fly on
        cur = nxt;
    }

    if (tid < HID) {
        out[(size_t)T_STEPS * BATCH * HID + (size_t)b * HID + tid] = hj;
    }
}

// ---------------------------------------------------------------------------
// Fallback (ws too small): monolithic kernel (known-good).
// ---------------------------------------------------------------------------
__global__ __launch_bounds__(512, 2)
void ctrnn_mono(const float* __restrict__ x, const float* __restrict__ hidden,
                const float* __restrict__ noise, const float* __restrict__ W_in,
                const float* __restrict__ b_in, const float* __restrict__ W_hh,
                const float* __restrict__ b_hh, float* __restrict__ out)
{
    const int tid  = threadIdx.x;
    const int j    = tid & (HID - 1);
    const int half = tid >> 8;
    const int b    = blockIdx.x;

    __shared__ __align__(16) float hbuf[2][HID];
    __shared__ __align__(16) float xbuf[2][INSZ];
    __shared__ __align__(16) float pbuf[HID];

    float whh[128];
    const float* wrow = &W_hh[j * HID + half * 128];
#pragma unroll
    for (int k = 0; k < 128; k += 4) {
        float4 v = *reinterpret_cast<const float4*>(&wrow[k]);
        whh[k] = v.x; whh[k+1] = v.y; whh[k+2] = v.z; whh[k+3] = v.w;
    }
    float win[32];
    const float* wirow = &W_in[j * INSZ + half * 32];
#pragma unroll
    for (int k = 0; k < 32; k += 4) {
        float4 v = *reinterpret_cast<const float4*>(&wirow[k]);
        win[k] = v.x; win[k+1] = v.y; win[k+2] = v.z; win[k+3] = v.w;
    }

    float bias = 0.f, hj = 0.f, noise_j = 0.f;
    if (half == 0) {
        bias = b_in[j] + b_hh[j];
        hj = hidden[b * HID + j];
        hbuf[0][j] = hj;
        noise_j = noise[j];
        if (j < INSZ / 4) {
            *reinterpret_cast<float4*>(&xbuf[0][4 * j]) =
                *reinterpret_cast<const float4*>(&x[(size_t)b * INSZ + 4 * j]);
        }
    }
    __syncthreads();

    const int hoff = half * 128;
    const int ioff = half * 32;
    int cur = 0;
#pragma unroll 1
    for (int t = 0; t < T_STEPS; ++t) {
        float4 xnext = make_float4(0.f, 0.f, 0.f, 0.f);
        float  nnext = 0.f;
        if (half == 1) {
            if (j < INSZ / 4 && t + 1 < T_STEPS) {
                xnext = *reinterpret_cast<const float4*>(
                    &x[((size_t)(t + 1) * BATCH + b) * INSZ + 4 * j]);
            }
        } else if (t + 1 < T_STEPS) {
            nnext = noise[(t + 1) * HID + j];
        }

        float a0 = 0.f, a1 = 0.f, a2 = 0.f, a3 = 0.f;
#pragma unroll
        for (int k = 0; k < 128; k += 4) {
            float4 hv = *reinterpret_cast<const float4*>(&hbuf[cur][hoff + k]);
            a0 = fmaf(whh[k],     hv.x, a0);
            a1 = fmaf(whh[k + 1], hv.y, a1);
            a2 = fmaf(whh[k + 2], hv.z, a2);
            a3 = fmaf(whh[k + 3], hv.w, a3);
        }
#pragma unroll
        for (int k = 0; k < 32; k += 4) {
            float4 xv = *reinterpret_cast<const float4*>(&xbuf[cur][ioff + k]);
            a0 = fmaf(win[k],     xv.x, a0);
            a1 = fmaf(win[k + 1], xv.y, a1);
            a2 = fmaf(win[k + 2], xv.z, a2);
            a3 = fmaf(win[k + 3], xv.w, a3);
        }
        const float acc = (a0 + a1) + (a2 + a3);

        if (half == 1) pbuf[j] = acc;
        __syncthreads();

        const int nxt = cur ^ 1;
        if (half == 0) {
            const float pre = acc + pbuf[j] + bias + noise_j;
            hj = fmaxf(fmaf(OMA_F, hj, ALPHA_F * pre), 0.f);
            out[((size_t)t * BATCH + b) * HID + j] = hj;
            hbuf[nxt][j] = hj;
            noise_j = nnext;
        } else if (j < INSZ / 4 && t + 1 < T_STEPS) {
            *reinterpret_cast<float4*>(&xbuf[nxt][4 * j]) = xnext;
        }
        __syncthreads();
        cur = nxt;
    }

    if (half == 0) {
        out[(size_t)T_STEPS * BATCH * HID + (size_t)b * HID + j] = hj;
    }
}

extern "C" void kernel_launch(void* const* d_in, const int* in_sizes, int n_in,
                              void* d_out, int out_size, void* d_ws, size_t ws_size,
                              hipStream_t stream) {
    const float* x      = (const float*)d_in[0];
    const float* hidden = (const float*)d_in[1];
    const float* noise  = (const float*)d_in[2];
    const float* W_in   = (const float*)d_in[3];
    const float* b_in   = (const float*)d_in[4];
    const float* W_hh   = (const float*)d_in[5];
    const float* b_hh   = (const float*)d_in[6];
    float* out = (float*)d_out;

    const size_t prex_bytes = (size_t)T_STEPS * BATCH * HID * sizeof(float);
    if (ws_size >= prex_bytes) {
        float* prex = (float*)d_ws;
        hipLaunchKernelGGL(ctrnn_prex3, dim3(512), dim3(512), 0, stream,
                           x, noise, W_in, b_in, b_hh, prex);
        hipLaunchKernelGGL(ctrnn_rec, dim3(BATCH), dim3(1024), 0, stream,
                           hidden, prex, W_hh, out);
    } else {
        hipLaunchKernelGGL(ctrnn_mono, dim3(BATCH), dim3(512), 0, stream,
                           x, hidden, noise, W_in, b_in, W_hh, b_hh, out);
    }
}